// Round 4
// baseline (643.204 us; speedup 1.0000x reference)
//
#include <hip/hip_runtime.h>

#define N_NODES 50000
#define N_EDGES 800000
#define SCAN_TILE 2048  // 256 threads x 8 elems
#define GEMM1_BLOCKS 768   // layer-1 gemm: 256-thread blocks, 3/CU
#define FUSED_BLOCKS 512   // fused agg+gemm: 512-thr blocks, 2/CU (empirical best)

// CSR build: per-chunk LDS histograms, u8-packed (NO global atomics — the
// memory-side atomic unit ceilings at ~7.6 ops/cycle device-wide, measured
// rounds 0-2). u8 counts: per-chunk per-node ~Binomial(12500,1/50000),
// P(>=256) ~ 1e-11.
#define HB 64                    // histogram chunks/blocks
#define EPB (N_EDGES / HB)       // 12500 edges per chunk (exact)
#define HGROUPS (EPB / 4)        // 3125 int4 groups per chunk
#define HWORDS (N_NODES / 4)     // 12500 uints (4 x u8 counts each) = 50 KB
#define SCANFILL_BLOCKS 960      // must be co-resident (4 blocks/CU x 240 CU)

static_assert(N_NODES < 65536, "col must fit in 16 bits for packed CSR");
static_assert(N_EDGES % (4 * HB) == 0, "chunking must be exact");
static_assert(N_NODES % 8 == 0, "scan tiles assume x8");

typedef __attribute__((ext_vector_type(4))) float f32x4;
typedef __attribute__((ext_vector_type(8))) short bf16x8;

__device__ inline unsigned short f32_to_bf16(float f) {
    unsigned int u = __builtin_bit_cast(unsigned int, f);
    u += 0x7FFF + ((u >> 16) & 1);  // RNE
    return (unsigned short)(u >> 16);
}
__device__ inline float bf16_to_f32(unsigned short h) {
    unsigned int u = ((unsigned int)h) << 16;
    return __builtin_bit_cast(float, u);
}

// ---------------------------------------------------------------------------
// MFMA phase, 256-thread variant (4 waves; wave w: rows w*16..+16, all tiles).
// Fragment layouts [measured m89/m91/m120].
// ---------------------------------------------------------------------------
template <int NOUT>
__device__ __forceinline__ void mfma_phase(const unsigned short* Xs,
                                           const unsigned short* Ws,
                                           unsigned short* __restrict__ Yb,
                                           int block_row, int N) {
    constexpr int KP = 128 + 8;
    constexpr int NT = NOUT / 16;
    const int tid = threadIdx.x;
    const int wave = tid >> 6;
    const int lane = tid & 63;
    const int m = lane & 15;
    const int quad = lane >> 4;
    const int rowbase = wave * 16;

    f32x4 acc[NT];
#pragma unroll
    for (int t = 0; t < NT; ++t) acc[t] = (f32x4){0.f, 0.f, 0.f, 0.f};

#pragma unroll
    for (int kt = 0; kt < 4; ++kt) {
        bf16x8 a = *reinterpret_cast<const bf16x8*>(
            Xs + (rowbase + m) * KP + kt * 32 + quad * 8);
#pragma unroll
        for (int t = 0; t < NT; ++t) {
            bf16x8 b = *reinterpret_cast<const bf16x8*>(
                Ws + (t * 16 + m) * KP + kt * 32 + quad * 8);
            acc[t] = __builtin_amdgcn_mfma_f32_16x16x32_bf16(a, b, acc[t], 0, 0, 0);
        }
    }

#pragma unroll
    for (int t = 0; t < NT; ++t) {
#pragma unroll
        for (int r = 0; r < 4; ++r) {
            int grow = block_row + rowbase + quad * 4 + r;
            if (grow < N)
                Yb[(size_t)grow * NOUT + t * 16 + m] = f32_to_bf16(acc[t][r]);
        }
    }
}

// ---------------------------------------------------------------------------
// Mega-dispatch 1: blocks 0..HB-1 build per-chunk LDS u8 histograms (rank +
// bhist, all LDS atomics); blocks HB.. run the layer-1 GEMM (W1 transposed
// from fp32 into LDS per-block — no prep dispatch). One 52 KB LDS union:
// hist needs 50 KB, gemm needs 52224 B; both keep 3 blocks/CU.
// ---------------------------------------------------------------------------
__global__ __launch_bounds__(256) void mega1(
    const float* __restrict__ x, const float* __restrict__ W1,
    unsigned short* __restrict__ Yb, int N, int ntiles,
    const int* __restrict__ erow, unsigned int* __restrict__ rank8,
    unsigned int* __restrict__ bhist, int* __restrict__ done,
    int* __restrict__ done2) {
    constexpr int KP = 128 + 8;
    __shared__ __align__(16) unsigned char smem[52224];
    const int tid = threadIdx.x;

    if (blockIdx.x < HB) {
        const int b = blockIdx.x;
        if (b == 0 && tid == 0) { *done = 0; *done2 = 0; }
        unsigned int* h = reinterpret_cast<unsigned int*>(smem);  // HWORDS
        int4* h4 = reinterpret_cast<int4*>(h);
        for (int i = tid; i < HWORDS / 4; i += 256) {
            int4 z = {0, 0, 0, 0};
            h4[i] = z;
        }
        __syncthreads();
        const int4* eg = reinterpret_cast<const int4*>(erow) + (size_t)b * HGROUPS;
        unsigned int* rg = rank8 + (size_t)b * HGROUPS;
        for (int g = tid; g < HGROUPS; g += 256) {
            int4 er = eg[g];
            unsigned int rk;
            int sh;
            unsigned int o;
            sh = (er.x & 3) << 3;
            o = atomicAdd(&h[er.x >> 2], 1u << sh);
            rk = (o >> sh) & 0xFFu;
            sh = (er.y & 3) << 3;
            o = atomicAdd(&h[er.y >> 2], 1u << sh);
            rk |= ((o >> sh) & 0xFFu) << 8;
            sh = (er.z & 3) << 3;
            o = atomicAdd(&h[er.z >> 2], 1u << sh);
            rk |= ((o >> sh) & 0xFFu) << 16;
            sh = (er.w & 3) << 3;
            o = atomicAdd(&h[er.w >> 2], 1u << sh);
            rk |= ((o >> sh) & 0xFFu) << 24;
            rg[g] = rk;
        }
        __syncthreads();
        int4* dst = reinterpret_cast<int4*>(bhist + (size_t)b * HWORDS);
        for (int i = tid; i < HWORDS / 4; i += 256) dst[i] = h4[i];
        return;
    }

    // ---- GEMM part
    const int gb = blockIdx.x - HB;
    unsigned short* Xs = reinterpret_cast<unsigned short*>(smem);   // 64*KP
    unsigned short* Ws = reinterpret_cast<unsigned short*>(smem) + 64 * KP;

    for (int idx = tid; idx < 128 * 128; idx += 256) {
        int k = idx >> 7, m = idx & 127;
        Ws[m * KP + k] = f32_to_bf16(W1[idx]);
    }

    for (int tile = gb; tile < ntiles; tile += GEMM1_BLOCKS) {
        const int block_row = tile * 64;
        for (int idx = tid; idx < 64 * 16; idx += 256) {
            int r = idx >> 4, ch = idx & 15;
            int gr = block_row + r;
            if (gr >= N) gr = N - 1;
            const float4* xp =
                reinterpret_cast<const float4*>(x + (size_t)gr * 128 + ch * 8);
            float4 a = xp[0], b = xp[1];
            uint4 o;
            o.x = (unsigned int)f32_to_bf16(a.x) | ((unsigned int)f32_to_bf16(a.y) << 16);
            o.y = (unsigned int)f32_to_bf16(a.z) | ((unsigned int)f32_to_bf16(a.w) << 16);
            o.z = (unsigned int)f32_to_bf16(b.x) | ((unsigned int)f32_to_bf16(b.y) << 16);
            o.w = (unsigned int)f32_to_bf16(b.z) | ((unsigned int)f32_to_bf16(b.w) << 16);
            *reinterpret_cast<uint4*>(Xs + r * KP + ch * 8) = o;
        }
        __syncthreads();
        mfma_phase<128>(Xs, Ws, Yb, block_row, N);
        __syncthreads();
    }
}

// ---------------------------------------------------------------------------
// Mega-dispatch 2: blocks 0..ntiles-1 scan (deg = sum of u8 chunk hists,
// spin-synced tile prefix -> rptr, then per-(chunk,node) bases bbase);
// then ALL 960 co-resident blocks spin on done2 and grid-stride the
// atomic-free CSR fill. 4 blocks/CU guaranteed by __launch_bounds__(256,4)
// so all 960 blocks are resident -> spin cannot deadlock.
// ---------------------------------------------------------------------------
__global__ __launch_bounds__(256, 4) void scan_fill(
    const unsigned int* __restrict__ bhist, int* __restrict__ tsum,
    int* __restrict__ done, int* __restrict__ done2,
    int* __restrict__ rptr, int* __restrict__ bbase,
    const int* __restrict__ erow, const int* __restrict__ ecol,
    const float* __restrict__ eval, const unsigned int* __restrict__ rank8,
    unsigned int* __restrict__ cpack, int n, int ntiles) {
    __shared__ int sums[256];
    __shared__ int off_s;
    const int t = threadIdx.x;
    const int b = blockIdx.x;

    if (b < ntiles) {
        const int base = b * SCAN_TILE + t * 8;
        const int widx2 = base >> 3;  // uint2 index within a chunk (6250/chunk)
        const uint2* bh2 = reinterpret_cast<const uint2*>(bhist);
        int v[8], pref[8];
#pragma unroll
        for (int i = 0; i < 8; ++i) v[i] = 0;
        if (base < n) {
            for (int hb = 0; hb < HB; ++hb) {
                uint2 p = bh2[hb * (HWORDS / 2) + widx2];
                v[0] += p.x & 0xFF; v[1] += (p.x >> 8) & 0xFF;
                v[2] += (p.x >> 16) & 0xFF; v[3] += p.x >> 24;
                v[4] += p.y & 0xFF; v[5] += (p.y >> 8) & 0xFF;
                v[6] += (p.y >> 16) & 0xFF; v[7] += p.y >> 24;
            }
        }
        int s = 0;
#pragma unroll
        for (int i = 0; i < 8; ++i) s += v[i];
        sums[t] = s;
        __syncthreads();
        for (int off = 1; off < 256; off <<= 1) {
            int x = (t >= off) ? sums[t - off] : 0;
            __syncthreads();
            sums[t] += x;
            __syncthreads();
        }
        int run = sums[t] - s;
#pragma unroll
        for (int i = 0; i < 8; ++i) {
            pref[i] = run;
            run += v[i];
        }
        if (t == 255) {
            tsum[b] = run;
            __threadfence();
            atomicAdd(done, 1);
        }
        if (t == 0) {
            while (__hip_atomic_load(done, __ATOMIC_ACQUIRE,
                                     __HIP_MEMORY_SCOPE_AGENT) < ntiles) {
            }
            __threadfence();
            int off = 0;
            for (int i = 0; i < b; ++i) off += tsum[i];
            off_s = off;
            if (b == 0) {
                int tot = 0;
                for (int i = 0; i < ntiles; ++i) tot += tsum[i];
                rptr[n] = tot;
            }
        }
        __syncthreads();
        const int off = off_s;
        if (base < n) {
            int rn[8];
#pragma unroll
            for (int i = 0; i < 8; ++i) rn[i] = pref[i] + off;
            int4 r0 = {rn[0], rn[1], rn[2], rn[3]};
            int4 r1 = {rn[4], rn[5], rn[6], rn[7]};
            *reinterpret_cast<int4*>(rptr + base) = r0;
            *reinterpret_cast<int4*>(rptr + base + 4) = r1;
            for (int hb = 0; hb < HB; ++hb) {
                int4 o0 = {rn[0], rn[1], rn[2], rn[3]};
                int4 o1 = {rn[4], rn[5], rn[6], rn[7]};
                int4* bb = reinterpret_cast<int4*>(
                    bbase + (size_t)hb * N_NODES + base);
                bb[0] = o0;
                bb[1] = o1;
                uint2 p = bh2[hb * (HWORDS / 2) + widx2];
                rn[0] += p.x & 0xFF; rn[1] += (p.x >> 8) & 0xFF;
                rn[2] += (p.x >> 16) & 0xFF; rn[3] += p.x >> 24;
                rn[4] += p.y & 0xFF; rn[5] += (p.y >> 8) & 0xFF;
                rn[6] += (p.y >> 16) & 0xFF; rn[7] += p.y >> 24;
            }
        }
        __syncthreads();
        if (t == 0) {
            __threadfence();
            atomicAdd(done2, 1);
        }
    }

    // ---- fill phase (all blocks; scan blocks join after their scan work)
    if (t == 0) {
        while (__hip_atomic_load(done2, __ATOMIC_ACQUIRE,
                                 __HIP_MEMORY_SCOPE_AGENT) < ntiles) {
        }
    }
    __syncthreads();
    __threadfence();
    const unsigned char* r8 = reinterpret_cast<const unsigned char*>(rank8);
    for (int e = b * 256 + t; e < N_EDGES; e += SCANFILL_BLOCKS * 256) {
        int row = erow[e];
        int slot = bbase[(size_t)(e / EPB) * N_NODES + row] + r8[e];
        unsigned int pk = (unsigned int)(ecol[e] & 0xFFFF) |
                          ((unsigned int)f32_to_bf16(eval[e]) << 16);
        cpack[slot] = pk;
    }
}

// ---------------------------------------------------------------------------
// MFMA phase, 512-thread variant (8 waves; wave w: rows (w&3)*16..+16,
// tile-columns (w>>2)*NT/2..+NT/2).
// ---------------------------------------------------------------------------
template <int NOUT>
__device__ __forceinline__ void mfma_phase512(const unsigned short* Xs,
                                              const unsigned short* Ws,
                                              unsigned short* __restrict__ Yb,
                                              int block_row, int N) {
    constexpr int KP = 128 + 8;
    constexpr int NT = NOUT / 16;
    constexpr int NTH = NT / 2;
    const int tid = threadIdx.x;
    const int wave = tid >> 6;
    const int lane = tid & 63;
    const int m = lane & 15;
    const int quad = lane >> 4;
    const int rowbase = (wave & 3) * 16;
    const int tbase = (wave >> 2) * NTH;

    f32x4 acc[NTH];
#pragma unroll
    for (int t = 0; t < NTH; ++t) acc[t] = (f32x4){0.f, 0.f, 0.f, 0.f};

#pragma unroll
    for (int kt = 0; kt < 4; ++kt) {
        bf16x8 a = *reinterpret_cast<const bf16x8*>(
            Xs + (rowbase + m) * KP + kt * 32 + quad * 8);
#pragma unroll
        for (int t = 0; t < NTH; ++t) {
            bf16x8 b = *reinterpret_cast<const bf16x8*>(
                Ws + ((tbase + t) * 16 + m) * KP + kt * 32 + quad * 8);
            acc[t] = __builtin_amdgcn_mfma_f32_16x16x32_bf16(a, b, acc[t], 0, 0, 0);
        }
    }

#pragma unroll
    for (int t = 0; t < NTH; ++t) {
#pragma unroll
        for (int r = 0; r < 4; ++r) {
            int grow = block_row + rowbase + quad * 4 + r;
            if (grow < N)
                Yb[(size_t)grow * NOUT + (tbase + t) * 16 + m] = f32_to_bf16(acc[t][r]);
        }
    }
}

// ---------------------------------------------------------------------------
// Fused aggregation + GEMM (layers 2,3), 512-thread blocks, 2 blocks/CU
// (16 waves/CU — empirical sweet spot). W transposed+converted from fp32
// into LDS per-block (no prep dispatch, no Wt buffers).
// Phase A: 32 groups x 16 lanes gather-aggregate 64 rows, +bias, ReLU,
// pack bf16 into LDS Xs. Phase B: mfma_phase512.
// ---------------------------------------------------------------------------
template <int NOUT>
__global__ __launch_bounds__(512, 4) void gemm_fused_agg(
    const unsigned short* __restrict__ S,
    const int* __restrict__ rptr, const unsigned int* __restrict__ cpack,
    const float* __restrict__ bias,
    const float* __restrict__ W,
    unsigned short* __restrict__ Yb,
    int N, int ntiles) {
    constexpr int KP = 128 + 8;
    __shared__ unsigned short Xs[64 * KP];
    __shared__ unsigned short Ws[NOUT * KP];
    const int tid = threadIdx.x;
    const int group = tid >> 4;   // 0..31
    const int f8 = tid & 15;

    for (int idx = tid; idx < 128 * NOUT; idx += 512) {
        int k = idx / NOUT, m = idx % NOUT;
        Ws[m * KP + k] = f32_to_bf16(W[idx]);
    }

    float bv[8];
#pragma unroll
    for (int i = 0; i < 8; ++i) bv[i] = bias[f8 * 8 + i];

    for (int tile = blockIdx.x; tile < ntiles; tile += gridDim.x) {
        const int block_row = tile * 64;
#pragma unroll
        for (int r4 = 0; r4 < 2; ++r4) {
            const int row = r4 * 32 + group;
            const int node = block_row + row;
            float acc[8];
#pragma unroll
            for (int i = 0; i < 8; ++i) acc[i] = bv[i];
            if (node < N) {
                const int beg = rptr[node];
                const int end = rptr[node + 1];
                int j = beg;
                for (; j + 8 <= end; j += 8) {
                    unsigned int p[8];
                    uint4 s[8];
#pragma unroll
                    for (int u = 0; u < 8; ++u) p[u] = cpack[j + u];
#pragma unroll
                    for (int u = 0; u < 8; ++u)
                        s[u] = *reinterpret_cast<const uint4*>(
                            S + (size_t)(p[u] & 0xFFFF) * 128 + f8 * 8);
#pragma unroll
                    for (int u = 0; u < 8; ++u) {
                        const float v = bf16_to_f32((unsigned short)(p[u] >> 16));
                        const unsigned short* sp =
                            reinterpret_cast<const unsigned short*>(&s[u]);
#pragma unroll
                        for (int i = 0; i < 8; ++i)
                            acc[i] = fmaf(v, bf16_to_f32(sp[i]), acc[i]);
                    }
                }
                if (j + 4 <= end) {
                    unsigned int p[4];
                    uint4 s[4];
#pragma unroll
                    for (int u = 0; u < 4; ++u) p[u] = cpack[j + u];
#pragma unroll
                    for (int u = 0; u < 4; ++u)
                        s[u] = *reinterpret_cast<const uint4*>(
                            S + (size_t)(p[u] & 0xFFFF) * 128 + f8 * 8);
#pragma unroll
                    for (int u = 0; u < 4; ++u) {
                        const float v = bf16_to_f32((unsigned short)(p[u] >> 16));
                        const unsigned short* sp =
                            reinterpret_cast<const unsigned short*>(&s[u]);
#pragma unroll
                        for (int i = 0; i < 8; ++i)
                            acc[i] = fmaf(v, bf16_to_f32(sp[i]), acc[i]);
                    }
                    j += 4;
                }
                if (j + 2 <= end) {
                    unsigned int p[2];
                    uint4 s[2];
#pragma unroll
                    for (int u = 0; u < 2; ++u) p[u] = cpack[j + u];
#pragma unroll
                    for (int u = 0; u < 2; ++u)
                        s[u] = *reinterpret_cast<const uint4*>(
                            S + (size_t)(p[u] & 0xFFFF) * 128 + f8 * 8);
#pragma unroll
                    for (int u = 0; u < 2; ++u) {
                        const float v = bf16_to_f32((unsigned short)(p[u] >> 16));
                        const unsigned short* sp =
                            reinterpret_cast<const unsigned short*>(&s[u]);
#pragma unroll
                        for (int i = 0; i < 8; ++i)
                            acc[i] = fmaf(v, bf16_to_f32(sp[i]), acc[i]);
                    }
                    j += 2;
                }
                if (j < end) {
                    unsigned int p = cpack[j];
                    uint4 s = *reinterpret_cast<const uint4*>(
                        S + (size_t)(p & 0xFFFF) * 128 + f8 * 8);
                    const float v = bf16_to_f32((unsigned short)(p >> 16));
                    const unsigned short* sp =
                        reinterpret_cast<const unsigned short*>(&s);
#pragma unroll
                    for (int i = 0; i < 8; ++i)
                        acc[i] = fmaf(v, bf16_to_f32(sp[i]), acc[i]);
                }
            }
            uint4 o;
            o.x = (unsigned int)f32_to_bf16(fmaxf(acc[0], 0.f)) |
                  ((unsigned int)f32_to_bf16(fmaxf(acc[1], 0.f)) << 16);
            o.y = (unsigned int)f32_to_bf16(fmaxf(acc[2], 0.f)) |
                  ((unsigned int)f32_to_bf16(fmaxf(acc[3], 0.f)) << 16);
            o.z = (unsigned int)f32_to_bf16(fmaxf(acc[4], 0.f)) |
                  ((unsigned int)f32_to_bf16(fmaxf(acc[5], 0.f)) << 16);
            o.w = (unsigned int)f32_to_bf16(fmaxf(acc[6], 0.f)) |
                  ((unsigned int)f32_to_bf16(fmaxf(acc[7], 0.f)) << 16);
            *reinterpret_cast<uint4*>(Xs + row * KP + f8 * 8) = o;
        }
        __syncthreads();
        mfma_phase512<NOUT>(Xs, Ws, Yb, block_row, N);
        __syncthreads();
    }
}

// ---------------------------------------------------------------------------
// Final aggregation: bf16 source [N,64], + bias, no activation, fp32 out.
// 8 lanes/node, 8 features/lane (uint4 = 16B gathers). Tiered unroll 8/4/2/1.
// ---------------------------------------------------------------------------
__global__ void aggregate_bf16_64(const unsigned short* __restrict__ S,
                                  const int* __restrict__ rptr,
                                  const unsigned int* __restrict__ cpack,
                                  const float* __restrict__ bias,
                                  float* __restrict__ out, int N) {
    const int node = blockIdx.x * (blockDim.x / 8) + threadIdx.x / 8;
    const int f8 = threadIdx.x & 7;
    if (node >= N) return;
    const int beg = rptr[node];
    const int end = rptr[node + 1];
    float acc[8];
#pragma unroll
    for (int i = 0; i < 8; ++i) acc[i] = bias[f8 * 8 + i];
    int j = beg;
    for (; j + 8 <= end; j += 8) {
        unsigned int p[8];
        uint4 s[8];
#pragma unroll
        for (int u = 0; u < 8; ++u) p[u] = cpack[j + u];
#pragma unroll
        for (int u = 0; u < 8; ++u)
            s[u] = *reinterpret_cast<const uint4*>(S + (size_t)(p[u] & 0xFFFF) * 64 + f8 * 8);
#pragma unroll
        for (int u = 0; u < 8; ++u) {
            const float v = bf16_to_f32((unsigned short)(p[u] >> 16));
            const unsigned short* sp = reinterpret_cast<const unsigned short*>(&s[u]);
#pragma unroll
            for (int i = 0; i < 8; ++i) acc[i] = fmaf(v, bf16_to_f32(sp[i]), acc[i]);
        }
    }
    if (j + 4 <= end) {
        unsigned int p[4];
        uint4 s[4];
#pragma unroll
        for (int u = 0; u < 4; ++u) p[u] = cpack[j + u];
#pragma unroll
        for (int u = 0; u < 4; ++u)
            s[u] = *reinterpret_cast<const uint4*>(S + (size_t)(p[u] & 0xFFFF) * 64 + f8 * 8);
#pragma unroll
        for (int u = 0; u < 4; ++u) {
            const float v = bf16_to_f32((unsigned short)(p[u] >> 16));
            const unsigned short* sp = reinterpret_cast<const unsigned short*>(&s[u]);
#pragma unroll
            for (int i = 0; i < 8; ++i) acc[i] = fmaf(v, bf16_to_f32(sp[i]), acc[i]);
        }
        j += 4;
    }
    if (j + 2 <= end) {
        unsigned int p[2];
        uint4 s[2];
#pragma unroll
        for (int u = 0; u < 2; ++u) p[u] = cpack[j + u];
#pragma unroll
        for (int u = 0; u < 2; ++u)
            s[u] = *reinterpret_cast<const uint4*>(S + (size_t)(p[u] & 0xFFFF) * 64 + f8 * 8);
#pragma unroll
        for (int u = 0; u < 2; ++u) {
            const float v = bf16_to_f32((unsigned short)(p[u] >> 16));
            const unsigned short* sp = reinterpret_cast<const unsigned short*>(&s[u]);
#pragma unroll
            for (int i = 0; i < 8; ++i) acc[i] = fmaf(v, bf16_to_f32(sp[i]), acc[i]);
        }
        j += 2;
    }
    if (j < end) {
        unsigned int p = cpack[j];
        uint4 s = *reinterpret_cast<const uint4*>(S + (size_t)(p & 0xFFFF) * 64 + f8 * 8);
        const float v = bf16_to_f32((unsigned short)(p >> 16));
        const unsigned short* sp = reinterpret_cast<const unsigned short*>(&s);
#pragma unroll
        for (int i = 0; i < 8; ++i) acc[i] = fmaf(v, bf16_to_f32(sp[i]), acc[i]);
    }
    float4 o0 = {acc[0], acc[1], acc[2], acc[3]};
    float4 o1 = {acc[4], acc[5], acc[6], acc[7]};
    float* op = out + (size_t)node * 64 + f8 * 8;
    *reinterpret_cast<float4*>(op) = o0;
    *reinterpret_cast<float4*>(op + 4) = o1;
}

extern "C" void kernel_launch(void* const* d_in, const int* in_sizes, int n_in,
                              void* d_out, int out_size, void* d_ws, size_t ws_size,
                              hipStream_t stream) {
    const float* x    = (const float*)d_in[0];
    const int*   erow = (const int*)d_in[1];
    const int*   ecol = (const int*)d_in[2];
    const float* eval = (const float*)d_in[3];
    const float* W1   = (const float*)d_in[4];
    const float* b1   = (const float*)d_in[5];
    const float* W2   = (const float*)d_in[6];
    const float* b2   = (const float*)d_in[7];
    const float* W3   = (const float*)d_in[8];
    const float* b3   = (const float*)d_in[9];
    float* out = (float*)d_out;

    const size_t nf = (size_t)N_NODES * 128;
    unsigned short* SA   = (unsigned short*)d_ws;            // support A (A1, A3)
    unsigned short* SB   = SA + nf;                          // support B (A2)
    unsigned int*  rank8 = (unsigned int*)(SB + nf);         // N_EDGES/4 uints (u8 ranks)
    unsigned int*  bhist = rank8 + N_EDGES / 4;              // HB * HWORDS uints
    int*   bbase  = (int*)(bhist + (size_t)HB * HWORDS);     // HB * N_NODES
    int*   rptr   = bbase + (size_t)HB * N_NODES;            // N_NODES + 1
    unsigned int* cpack = (unsigned int*)(rptr + N_NODES + 1);  // N_EDGES
    int*   stsum  = (int*)(cpack + N_EDGES);                 // 32 (scan tiles)
    int*   done   = stsum + 64;                              // own cache line
    int*   done2  = stsum + 80;                              // own cache line

    const int blk = 256;
    const int ntiles_g = (N_NODES + 63) / 64;
    const int agg_grid = (int)(((long long)N_NODES * 8 + blk - 1) / blk);
    const int ntiles = (N_NODES + SCAN_TILE - 1) / SCAN_TILE;

    // ---- 1. mega1: LDS chunk-histograms + rank (blocks 0..63, overlapped
    //         with) layer-1 GEMM with inline W1 transpose (blocks 64..831)
    mega1<<<HB + GEMM1_BLOCKS, blk, 0, stream>>>(
        x, W1, SA, N_NODES, ntiles_g, erow, rank8, bhist, done, done2);

    // ---- 2. scan (25 blocks) + atomic-free CSR fill (all 960 blocks)
    scan_fill<<<SCANFILL_BLOCKS, blk, 0, stream>>>(
        bhist, stsum, done, done2, rptr, bbase, erow, ecol, eval, rank8,
        cpack, N_NODES, ntiles);

    // ---- 3. Layer 2: fused agg(A1)+ReLU+b1 -> GEMM W2 -> A2
    gemm_fused_agg<128><<<FUSED_BLOCKS, 512, 0, stream>>>(
        SA, rptr, cpack, b1, W2, SB, N_NODES, ntiles_g);

    // ---- 4. Layer 3: fused agg(A2)+ReLU+b2 -> GEMM W3 -> A3 (64-wide)
    gemm_fused_agg<64><<<FUSED_BLOCKS, 512, 0, stream>>>(
        SB, rptr, cpack, b2, W3, SA, N_NODES, ntiles_g);

    // ---- 5. Final aggregation: A3 + b3 -> out (fp32)
    aggregate_bf16_64<<<agg_grid, blk, 0, stream>>>(SA, rptr, cpack, b3, out, N_NODES);
}

// Round 5
// 228.247 us; speedup vs baseline: 2.8180x; 2.8180x over previous
//
#include <hip/hip_runtime.h>

#define N_NODES 50000
#define N_EDGES 800000
#define SCAN_TILE 2048  // 256 threads x 8 elems
#define GEMM1_BLOCKS 768   // layer-1 gemm: 256-thread blocks, 3/CU
#define FUSED_BLOCKS 512   // fused agg+gemm: 512-thr blocks, 2/CU (empirical best)
#define FILL_BLOCKS ((N_EDGES + 255) / 256)  // 3125

// CSR build: per-chunk LDS histograms, u8-packed (NO global atomics — the
// memory-side atomic unit ceilings at ~7.6 ops/cycle device-wide, measured
// rounds 0-2). u8 counts: per-chunk per-node ~Binomial(12500,1/50000),
// P(>=256) ~ 1e-11. NOTE (round 4 lesson): do NOT sync scan->fill with a
// 960-block spin — spin-storms saturate the coherence point. Dispatch
// boundary is the cheap barrier.
#define HB 64                    // histogram chunks/blocks
#define EPB (N_EDGES / HB)       // 12500 edges per chunk (exact)
#define HGROUPS (EPB / 4)        // 3125 int4 groups per chunk
#define HWORDS (N_NODES / 4)     // 12500 uints (4 x u8 counts each) = 50 KB

static_assert(N_NODES < 65536, "col must fit in 16 bits for packed CSR");
static_assert(N_EDGES % (4 * HB) == 0, "chunking must be exact");
static_assert(N_NODES % 8 == 0, "scan tiles assume x8");

typedef __attribute__((ext_vector_type(4))) float f32x4;
typedef __attribute__((ext_vector_type(8))) short bf16x8;

__device__ inline unsigned short f32_to_bf16(float f) {
    unsigned int u = __builtin_bit_cast(unsigned int, f);
    u += 0x7FFF + ((u >> 16) & 1);  // RNE
    return (unsigned short)(u >> 16);
}
__device__ inline float bf16_to_f32(unsigned short h) {
    unsigned int u = ((unsigned int)h) << 16;
    return __builtin_bit_cast(float, u);
}

// ---------------------------------------------------------------------------
// MFMA phase, 256-thread variant (4 waves; wave w: rows w*16..+16, all tiles).
// Fragment layouts [measured m89/m91/m120].
// ---------------------------------------------------------------------------
template <int NOUT>
__device__ __forceinline__ void mfma_phase(const unsigned short* Xs,
                                           const unsigned short* Ws,
                                           unsigned short* __restrict__ Yb,
                                           int block_row, int N) {
    constexpr int KP = 128 + 8;
    constexpr int NT = NOUT / 16;
    const int tid = threadIdx.x;
    const int wave = tid >> 6;
    const int lane = tid & 63;
    const int m = lane & 15;
    const int quad = lane >> 4;
    const int rowbase = wave * 16;

    f32x4 acc[NT];
#pragma unroll
    for (int t = 0; t < NT; ++t) acc[t] = (f32x4){0.f, 0.f, 0.f, 0.f};

#pragma unroll
    for (int kt = 0; kt < 4; ++kt) {
        bf16x8 a = *reinterpret_cast<const bf16x8*>(
            Xs + (rowbase + m) * KP + kt * 32 + quad * 8);
#pragma unroll
        for (int t = 0; t < NT; ++t) {
            bf16x8 b = *reinterpret_cast<const bf16x8*>(
                Ws + (t * 16 + m) * KP + kt * 32 + quad * 8);
            acc[t] = __builtin_amdgcn_mfma_f32_16x16x32_bf16(a, b, acc[t], 0, 0, 0);
        }
    }

#pragma unroll
    for (int t = 0; t < NT; ++t) {
#pragma unroll
        for (int r = 0; r < 4; ++r) {
            int grow = block_row + rowbase + quad * 4 + r;
            if (grow < N)
                Yb[(size_t)grow * NOUT + t * 16 + m] = f32_to_bf16(acc[t][r]);
        }
    }
}

// ---------------------------------------------------------------------------
// Mega-dispatch 1: blocks 0..HB-1 build per-chunk LDS u8 histograms (rank +
// bhist, all LDS atomics); blocks HB.. run the layer-1 GEMM (W1 transposed
// from fp32 into LDS per-block — no prep dispatch). One 52 KB LDS union;
// both paths keep 3 blocks/CU.
// ---------------------------------------------------------------------------
__global__ __launch_bounds__(256) void mega1(
    const float* __restrict__ x, const float* __restrict__ W1,
    unsigned short* __restrict__ Yb, int N, int ntiles,
    const int* __restrict__ erow, unsigned int* __restrict__ rank8,
    unsigned int* __restrict__ bhist, int* __restrict__ done) {
    constexpr int KP = 128 + 8;
    __shared__ __align__(16) unsigned char smem[52224];
    const int tid = threadIdx.x;

    if (blockIdx.x < HB) {
        const int b = blockIdx.x;
        if (b == 0 && tid == 0) *done = 0;
        unsigned int* h = reinterpret_cast<unsigned int*>(smem);  // HWORDS
        int4* h4 = reinterpret_cast<int4*>(h);
        for (int i = tid; i < HWORDS / 4; i += 256) {
            int4 z = {0, 0, 0, 0};
            h4[i] = z;
        }
        __syncthreads();
        const int4* eg = reinterpret_cast<const int4*>(erow) + (size_t)b * HGROUPS;
        unsigned int* rg = rank8 + (size_t)b * HGROUPS;
        for (int g = tid; g < HGROUPS; g += 256) {
            int4 er = eg[g];
            unsigned int rk;
            int sh;
            unsigned int o;
            sh = (er.x & 3) << 3;
            o = atomicAdd(&h[er.x >> 2], 1u << sh);
            rk = (o >> sh) & 0xFFu;
            sh = (er.y & 3) << 3;
            o = atomicAdd(&h[er.y >> 2], 1u << sh);
            rk |= ((o >> sh) & 0xFFu) << 8;
            sh = (er.z & 3) << 3;
            o = atomicAdd(&h[er.z >> 2], 1u << sh);
            rk |= ((o >> sh) & 0xFFu) << 16;
            sh = (er.w & 3) << 3;
            o = atomicAdd(&h[er.w >> 2], 1u << sh);
            rk |= ((o >> sh) & 0xFFu) << 24;
            rg[g] = rk;
        }
        __syncthreads();
        int4* dst = reinterpret_cast<int4*>(bhist + (size_t)b * HWORDS);
        for (int i = tid; i < HWORDS / 4; i += 256) dst[i] = h4[i];
        return;
    }

    // ---- GEMM part
    const int gb = blockIdx.x - HB;
    unsigned short* Xs = reinterpret_cast<unsigned short*>(smem);   // 64*KP
    unsigned short* Ws = reinterpret_cast<unsigned short*>(smem) + 64 * KP;

    for (int idx = tid; idx < 128 * 128; idx += 256) {
        int k = idx >> 7, m = idx & 127;
        Ws[m * KP + k] = f32_to_bf16(W1[idx]);
    }

    for (int tile = gb; tile < ntiles; tile += GEMM1_BLOCKS) {
        const int block_row = tile * 64;
        for (int idx = tid; idx < 64 * 16; idx += 256) {
            int r = idx >> 4, ch = idx & 15;
            int gr = block_row + r;
            if (gr >= N) gr = N - 1;
            const float4* xp =
                reinterpret_cast<const float4*>(x + (size_t)gr * 128 + ch * 8);
            float4 a = xp[0], b = xp[1];
            uint4 o;
            o.x = (unsigned int)f32_to_bf16(a.x) | ((unsigned int)f32_to_bf16(a.y) << 16);
            o.y = (unsigned int)f32_to_bf16(a.z) | ((unsigned int)f32_to_bf16(a.w) << 16);
            o.z = (unsigned int)f32_to_bf16(b.x) | ((unsigned int)f32_to_bf16(b.y) << 16);
            o.w = (unsigned int)f32_to_bf16(b.z) | ((unsigned int)f32_to_bf16(b.w) << 16);
            *reinterpret_cast<uint4*>(Xs + r * KP + ch * 8) = o;
        }
        __syncthreads();
        mfma_phase<128>(Xs, Ws, Yb, block_row, N);
        __syncthreads();
    }
}

// ---------------------------------------------------------------------------
// Scan (25 blocks, internal spin over 25 producers — safe at this scale):
// deg = sum of u8 chunk hists -> rptr, plus per-(chunk,node) bases bbase.
// ---------------------------------------------------------------------------
__global__ void scan_fused(const unsigned int* __restrict__ bhist,
                           int* __restrict__ tsum, int* __restrict__ done,
                           int* __restrict__ rptr, int* __restrict__ bbase,
                           int n, int ntiles) {
    __shared__ int sums[256];
    __shared__ int off_s;
    const int t = threadIdx.x;
    const int b = blockIdx.x;
    const int base = b * SCAN_TILE + t * 8;
    const int widx2 = base >> 3;  // uint2 index within a chunk (6250/chunk)
    const uint2* bh2 = reinterpret_cast<const uint2*>(bhist);
    int v[8], pref[8];
#pragma unroll
    for (int i = 0; i < 8; ++i) v[i] = 0;
    if (base < n) {
        for (int hb = 0; hb < HB; ++hb) {
            uint2 p = bh2[hb * (HWORDS / 2) + widx2];
            v[0] += p.x & 0xFF; v[1] += (p.x >> 8) & 0xFF;
            v[2] += (p.x >> 16) & 0xFF; v[3] += p.x >> 24;
            v[4] += p.y & 0xFF; v[5] += (p.y >> 8) & 0xFF;
            v[6] += (p.y >> 16) & 0xFF; v[7] += p.y >> 24;
        }
    }
    int s = 0;
#pragma unroll
    for (int i = 0; i < 8; ++i) s += v[i];
    sums[t] = s;
    __syncthreads();
    for (int off = 1; off < 256; off <<= 1) {
        int x = (t >= off) ? sums[t - off] : 0;
        __syncthreads();
        sums[t] += x;
        __syncthreads();
    }
    int run = sums[t] - s;
#pragma unroll
    for (int i = 0; i < 8; ++i) {
        pref[i] = run;
        run += v[i];
    }
    if (t == 255) {
        tsum[b] = run;
        __threadfence();
        atomicAdd(done, 1);
    }
    if (t == 0) {
        while (__hip_atomic_load(done, __ATOMIC_ACQUIRE, __HIP_MEMORY_SCOPE_AGENT) <
               ntiles) {
        }
        __threadfence();
        int off = 0;
        for (int i = 0; i < b; ++i) off += tsum[i];
        off_s = off;
        if (b == 0) {
            int tot = 0;
            for (int i = 0; i < ntiles; ++i) tot += tsum[i];
            rptr[n] = tot;
        }
    }
    __syncthreads();
    const int off = off_s;
    if (base < n) {
        int rn[8];
#pragma unroll
        for (int i = 0; i < 8; ++i) rn[i] = pref[i] + off;
        int4 r0 = {rn[0], rn[1], rn[2], rn[3]};
        int4 r1 = {rn[4], rn[5], rn[6], rn[7]};
        *reinterpret_cast<int4*>(rptr + base) = r0;
        *reinterpret_cast<int4*>(rptr + base + 4) = r1;
        for (int hb = 0; hb < HB; ++hb) {
            int4 o0 = {rn[0], rn[1], rn[2], rn[3]};
            int4 o1 = {rn[4], rn[5], rn[6], rn[7]};
            int4* bb = reinterpret_cast<int4*>(bbase + (size_t)hb * N_NODES + base);
            bb[0] = o0;
            bb[1] = o1;
            uint2 p = bh2[hb * (HWORDS / 2) + widx2];
            rn[0] += p.x & 0xFF; rn[1] += (p.x >> 8) & 0xFF;
            rn[2] += (p.x >> 16) & 0xFF; rn[3] += p.x >> 24;
            rn[4] += p.y & 0xFF; rn[5] += (p.y >> 8) & 0xFF;
            rn[6] += (p.y >> 16) & 0xFF; rn[7] += p.y >> 24;
        }
    }
}

// ---------------------------------------------------------------------------
// Atomic-free CSR fill: slot = bbase[chunk(e)][row] + rank8[e]; 4B store.
// ---------------------------------------------------------------------------
__global__ void fill_csr(const int* __restrict__ erow, const int* __restrict__ ecol,
                         const float* __restrict__ eval, const int* __restrict__ bbase,
                         const unsigned int* __restrict__ rank8,
                         unsigned int* __restrict__ cpack) {
    int e = blockIdx.x * blockDim.x + threadIdx.x;
    if (e >= N_EDGES) return;
    const unsigned char* r8 = reinterpret_cast<const unsigned char*>(rank8);
    int slot = bbase[(size_t)(e / EPB) * N_NODES + erow[e]] + r8[e];
    unsigned int p = (unsigned int)(ecol[e] & 0xFFFF) |
                     ((unsigned int)f32_to_bf16(eval[e]) << 16);
    cpack[slot] = p;
}

// ---------------------------------------------------------------------------
// MFMA phase, 512-thread variant (8 waves; wave w: rows (w&3)*16..+16,
// tile-columns (w>>2)*NT/2..+NT/2).
// ---------------------------------------------------------------------------
template <int NOUT>
__device__ __forceinline__ void mfma_phase512(const unsigned short* Xs,
                                              const unsigned short* Ws,
                                              unsigned short* __restrict__ Yb,
                                              int block_row, int N) {
    constexpr int KP = 128 + 8;
    constexpr int NT = NOUT / 16;
    constexpr int NTH = NT / 2;
    const int tid = threadIdx.x;
    const int wave = tid >> 6;
    const int lane = tid & 63;
    const int m = lane & 15;
    const int quad = lane >> 4;
    const int rowbase = (wave & 3) * 16;
    const int tbase = (wave >> 2) * NTH;

    f32x4 acc[NTH];
#pragma unroll
    for (int t = 0; t < NTH; ++t) acc[t] = (f32x4){0.f, 0.f, 0.f, 0.f};

#pragma unroll
    for (int kt = 0; kt < 4; ++kt) {
        bf16x8 a = *reinterpret_cast<const bf16x8*>(
            Xs + (rowbase + m) * KP + kt * 32 + quad * 8);
#pragma unroll
        for (int t = 0; t < NTH; ++t) {
            bf16x8 b = *reinterpret_cast<const bf16x8*>(
                Ws + ((tbase + t) * 16 + m) * KP + kt * 32 + quad * 8);
            acc[t] = __builtin_amdgcn_mfma_f32_16x16x32_bf16(a, b, acc[t], 0, 0, 0);
        }
    }

#pragma unroll
    for (int t = 0; t < NTH; ++t) {
#pragma unroll
        for (int r = 0; r < 4; ++r) {
            int grow = block_row + rowbase + quad * 4 + r;
            if (grow < N)
                Yb[(size_t)grow * NOUT + (tbase + t) * 16 + m] = f32_to_bf16(acc[t][r]);
        }
    }
}

// ---------------------------------------------------------------------------
// Fused aggregation + GEMM (layers 2,3), 512-thread blocks, 2 blocks/CU
// (16 waves/CU — empirical sweet spot). W transposed+converted from fp32
// into LDS per-block (no prep dispatch, no Wt buffers).
// Phase A: 32 groups x 16 lanes gather-aggregate 64 rows, +bias, ReLU,
// pack bf16 into LDS Xs. Phase B: mfma_phase512.
// ---------------------------------------------------------------------------
template <int NOUT>
__global__ __launch_bounds__(512, 4) void gemm_fused_agg(
    const unsigned short* __restrict__ S,
    const int* __restrict__ rptr, const unsigned int* __restrict__ cpack,
    const float* __restrict__ bias,
    const float* __restrict__ W,
    unsigned short* __restrict__ Yb,
    int N, int ntiles) {
    constexpr int KP = 128 + 8;
    __shared__ unsigned short Xs[64 * KP];
    __shared__ unsigned short Ws[NOUT * KP];
    const int tid = threadIdx.x;
    const int group = tid >> 4;   // 0..31
    const int f8 = tid & 15;

    for (int idx = tid; idx < 128 * NOUT; idx += 512) {
        int k = idx / NOUT, m = idx % NOUT;
        Ws[m * KP + k] = f32_to_bf16(W[idx]);
    }

    float bv[8];
#pragma unroll
    for (int i = 0; i < 8; ++i) bv[i] = bias[f8 * 8 + i];

    for (int tile = blockIdx.x; tile < ntiles; tile += gridDim.x) {
        const int block_row = tile * 64;
#pragma unroll
        for (int r4 = 0; r4 < 2; ++r4) {
            const int row = r4 * 32 + group;
            const int node = block_row + row;
            float acc[8];
#pragma unroll
            for (int i = 0; i < 8; ++i) acc[i] = bv[i];
            if (node < N) {
                const int beg = rptr[node];
                const int end = rptr[node + 1];
                int j = beg;
                for (; j + 8 <= end; j += 8) {
                    unsigned int p[8];
                    uint4 s[8];
#pragma unroll
                    for (int u = 0; u < 8; ++u) p[u] = cpack[j + u];
#pragma unroll
                    for (int u = 0; u < 8; ++u)
                        s[u] = *reinterpret_cast<const uint4*>(
                            S + (size_t)(p[u] & 0xFFFF) * 128 + f8 * 8);
#pragma unroll
                    for (int u = 0; u < 8; ++u) {
                        const float v = bf16_to_f32((unsigned short)(p[u] >> 16));
                        const unsigned short* sp =
                            reinterpret_cast<const unsigned short*>(&s[u]);
#pragma unroll
                        for (int i = 0; i < 8; ++i)
                            acc[i] = fmaf(v, bf16_to_f32(sp[i]), acc[i]);
                    }
                }
                if (j + 4 <= end) {
                    unsigned int p[4];
                    uint4 s[4];
#pragma unroll
                    for (int u = 0; u < 4; ++u) p[u] = cpack[j + u];
#pragma unroll
                    for (int u = 0; u < 4; ++u)
                        s[u] = *reinterpret_cast<const uint4*>(
                            S + (size_t)(p[u] & 0xFFFF) * 128 + f8 * 8);
#pragma unroll
                    for (int u = 0; u < 4; ++u) {
                        const float v = bf16_to_f32((unsigned short)(p[u] >> 16));
                        const unsigned short* sp =
                            reinterpret_cast<const unsigned short*>(&s[u]);
#pragma unroll
                        for (int i = 0; i < 8; ++i)
                            acc[i] = fmaf(v, bf16_to_f32(sp[i]), acc[i]);
                    }
                    j += 4;
                }
                if (j + 2 <= end) {
                    unsigned int p[2];
                    uint4 s[2];
#pragma unroll
                    for (int u = 0; u < 2; ++u) p[u] = cpack[j + u];
#pragma unroll
                    for (int u = 0; u < 2; ++u)
                        s[u] = *reinterpret_cast<const uint4*>(
                            S + (size_t)(p[u] & 0xFFFF) * 128 + f8 * 8);
#pragma unroll
                    for (int u = 0; u < 2; ++u) {
                        const float v = bf16_to_f32((unsigned short)(p[u] >> 16));
                        const unsigned short* sp =
                            reinterpret_cast<const unsigned short*>(&s[u]);
#pragma unroll
                        for (int i = 0; i < 8; ++i)
                            acc[i] = fmaf(v, bf16_to_f32(sp[i]), acc[i]);
                    }
                    j += 2;
                }
                if (j < end) {
                    unsigned int p = cpack[j];
                    uint4 s = *reinterpret_cast<const uint4*>(
                        S + (size_t)(p & 0xFFFF) * 128 + f8 * 8);
                    const float v = bf16_to_f32((unsigned short)(p >> 16));
                    const unsigned short* sp =
                        reinterpret_cast<const unsigned short*>(&s);
#pragma unroll
                    for (int i = 0; i < 8; ++i)
                        acc[i] = fmaf(v, bf16_to_f32(sp[i]), acc[i]);
                }
            }
            uint4 o;
            o.x = (unsigned int)f32_to_bf16(fmaxf(acc[0], 0.f)) |
                  ((unsigned int)f32_to_bf16(fmaxf(acc[1], 0.f)) << 16);
            o.y = (unsigned int)f32_to_bf16(fmaxf(acc[2], 0.f)) |
                  ((unsigned int)f32_to_bf16(fmaxf(acc[3], 0.f)) << 16);
            o.z = (unsigned int)f32_to_bf16(fmaxf(acc[4], 0.f)) |
                  ((unsigned int)f32_to_bf16(fmaxf(acc[5], 0.f)) << 16);
            o.w = (unsigned int)f32_to_bf16(fmaxf(acc[6], 0.f)) |
                  ((unsigned int)f32_to_bf16(fmaxf(acc[7], 0.f)) << 16);
            *reinterpret_cast<uint4*>(Xs + row * KP + f8 * 8) = o;
        }
        __syncthreads();
        mfma_phase512<NOUT>(Xs, Ws, Yb, block_row, N);
        __syncthreads();
    }
}

// ---------------------------------------------------------------------------
// Final aggregation: bf16 source [N,64], + bias, no activation, fp32 out.
// 8 lanes/node, 8 features/lane (uint4 = 16B gathers). Tiered unroll 8/4/2/1.
// ---------------------------------------------------------------------------
__global__ void aggregate_bf16_64(const unsigned short* __restrict__ S,
                                  const int* __restrict__ rptr,
                                  const unsigned int* __restrict__ cpack,
                                  const float* __restrict__ bias,
                                  float* __restrict__ out, int N) {
    const int node = blockIdx.x * (blockDim.x / 8) + threadIdx.x / 8;
    const int f8 = threadIdx.x & 7;
    if (node >= N) return;
    const int beg = rptr[node];
    const int end = rptr[node + 1];
    float acc[8];
#pragma unroll
    for (int i = 0; i < 8; ++i) acc[i] = bias[f8 * 8 + i];
    int j = beg;
    for (; j + 8 <= end; j += 8) {
        unsigned int p[8];
        uint4 s[8];
#pragma unroll
        for (int u = 0; u < 8; ++u) p[u] = cpack[j + u];
#pragma unroll
        for (int u = 0; u < 8; ++u)
            s[u] = *reinterpret_cast<const uint4*>(S + (size_t)(p[u] & 0xFFFF) * 64 + f8 * 8);
#pragma unroll
        for (int u = 0; u < 8; ++u) {
            const float v = bf16_to_f32((unsigned short)(p[u] >> 16));
            const unsigned short* sp = reinterpret_cast<const unsigned short*>(&s[u]);
#pragma unroll
            for (int i = 0; i < 8; ++i) acc[i] = fmaf(v, bf16_to_f32(sp[i]), acc[i]);
        }
    }
    if (j + 4 <= end) {
        unsigned int p[4];
        uint4 s[4];
#pragma unroll
        for (int u = 0; u < 4; ++u) p[u] = cpack[j + u];
#pragma unroll
        for (int u = 0; u < 4; ++u)
            s[u] = *reinterpret_cast<const uint4*>(S + (size_t)(p[u] & 0xFFFF) * 64 + f8 * 8);
#pragma unroll
        for (int u = 0; u < 4; ++u) {
            const float v = bf16_to_f32((unsigned short)(p[u] >> 16));
            const unsigned short* sp = reinterpret_cast<const unsigned short*>(&s[u]);
#pragma unroll
            for (int i = 0; i < 8; ++i) acc[i] = fmaf(v, bf16_to_f32(sp[i]), acc[i]);
        }
        j += 4;
    }
    if (j + 2 <= end) {
        unsigned int p[2];
        uint4 s[2];
#pragma unroll
        for (int u = 0; u < 2; ++u) p[u] = cpack[j + u];
#pragma unroll
        for (int u = 0; u < 2; ++u)
            s[u] = *reinterpret_cast<const uint4*>(S + (size_t)(p[u] & 0xFFFF) * 64 + f8 * 8);
#pragma unroll
        for (int u = 0; u < 2; ++u) {
            const float v = bf16_to_f32((unsigned short)(p[u] >> 16));
            const unsigned short* sp = reinterpret_cast<const unsigned short*>(&s[u]);
#pragma unroll
            for (int i = 0; i < 8; ++i) acc[i] = fmaf(v, bf16_to_f32(sp[i]), acc[i]);
        }
        j += 2;
    }
    if (j < end) {
        unsigned int p = cpack[j];
        uint4 s = *reinterpret_cast<const uint4*>(S + (size_t)(p & 0xFFFF) * 64 + f8 * 8);
        const float v = bf16_to_f32((unsigned short)(p >> 16));
        const unsigned short* sp = reinterpret_cast<const unsigned short*>(&s);
#pragma unroll
        for (int i = 0; i < 8; ++i) acc[i] = fmaf(v, bf16_to_f32(sp[i]), acc[i]);
    }
    float4 o0 = {acc[0], acc[1], acc[2], acc[3]};
    float4 o1 = {acc[4], acc[5], acc[6], acc[7]};
    float* op = out + (size_t)node * 64 + f8 * 8;
    *reinterpret_cast<float4*>(op) = o0;
    *reinterpret_cast<float4*>(op + 4) = o1;
}

extern "C" void kernel_launch(void* const* d_in, const int* in_sizes, int n_in,
                              void* d_out, int out_size, void* d_ws, size_t ws_size,
                              hipStream_t stream) {
    const float* x    = (const float*)d_in[0];
    const int*   erow = (const int*)d_in[1];
    const int*   ecol = (const int*)d_in[2];
    const float* eval = (const float*)d_in[3];
    const float* W1   = (const float*)d_in[4];
    const float* b1   = (const float*)d_in[5];
    const float* W2   = (const float*)d_in[6];
    const float* b2   = (const float*)d_in[7];
    const float* W3   = (const float*)d_in[8];
    const float* b3   = (const float*)d_in[9];
    float* out = (float*)d_out;

    const size_t nf = (size_t)N_NODES * 128;
    unsigned short* SA   = (unsigned short*)d_ws;            // support A (A1, A3)
    unsigned short* SB   = SA + nf;                          // support B (A2)
    unsigned int*  rank8 = (unsigned int*)(SB + nf);         // N_EDGES/4 uints (u8 ranks)
    unsigned int*  bhist = rank8 + N_EDGES / 4;              // HB * HWORDS uints
    int*   bbase  = (int*)(bhist + (size_t)HB * HWORDS);     // HB * N_NODES
    int*   rptr   = bbase + (size_t)HB * N_NODES;            // N_NODES + 1
    unsigned int* cpack = (unsigned int*)(rptr + N_NODES + 1);  // N_EDGES
    int*   stsum  = (int*)(cpack + N_EDGES);                 // 32 (scan tiles)
    int*   done   = stsum + 64;                              // own cache line

    const int blk = 256;
    const int ntiles_g = (N_NODES + 63) / 64;
    const int agg_grid = (int)(((long long)N_NODES * 8 + blk - 1) / blk);
    const int ntiles = (N_NODES + SCAN_TILE - 1) / SCAN_TILE;

    // ---- 1. mega1: LDS chunk-histograms + rank (blocks 0..63) overlapped
    //         with layer-1 GEMM + inline W1 transpose (blocks 64..831)
    mega1<<<HB + GEMM1_BLOCKS, blk, 0, stream>>>(
        x, W1, SA, N_NODES, ntiles_g, erow, rank8, bhist, done);

    // ---- 2. scan -> rptr + per-chunk slot bases bbase (25 blocks)
    scan_fused<<<ntiles, blk, 0, stream>>>(bhist, stsum, done, rptr, bbase,
                                           N_NODES, ntiles);

    // ---- 3. atomic-free CSR fill
    fill_csr<<<FILL_BLOCKS, blk, 0, stream>>>(erow, ecol, eval, bbase, rank8, cpack);

    // ---- 4. Layer 2: fused agg(A1)+ReLU+b1 -> GEMM W2 -> A2
    gemm_fused_agg<128><<<FUSED_BLOCKS, 512, 0, stream>>>(
        SA, rptr, cpack, b1, W2, SB, N_NODES, ntiles_g);

    // ---- 5. Layer 3: fused agg(A2)+ReLU+b2 -> GEMM W3 -> A3 (64-wide)
    gemm_fused_agg<64><<<FUSED_BLOCKS, 512, 0, stream>>>(
        SB, rptr, cpack, b2, W3, SA, N_NODES, ntiles_g);

    // ---- 6. Final aggregation: A3 + b3 -> out (fp32)
    aggregate_bf16_64<<<agg_grid, blk, 0, stream>>>(SA, rptr, cpack, b3, out, N_NODES);
}